// Round 1
// baseline (1401.505 us; speedup 1.0000x reference)
//
#include <hip/hip_runtime.h>
#include <hip/hip_fp16.h>

// Problem shape (fixed by reference): x[4,2048,4096] f32, w[16384,4096] f32, bias[16384] f32
#define M_DIM 8192
#define K_DIM 4096
#define N_DIM 16384
#define NW_ELEMS (16384 * 4096)  // 67108864
#define NX_ELEMS (8192 * 4096)   // 33554432

typedef _Float16 half8 __attribute__((ext_vector_type(8)));
typedef float f32x4 __attribute__((ext_vector_type(4)));

// ---------------- gamma = max(mean(|clip(w,-2,2)|), 1e-4), f64 accumulation ----------------

__global__ void zero_gsum(double* g) {
    if (threadIdx.x == 0 && blockIdx.x == 0) *g = 0.0;
}

__global__ void gamma_reduce(const float4* __restrict__ w4, double* __restrict__ gsum, int n4) {
    double acc = 0.0;
    int stride = gridDim.x * blockDim.x;
    for (int i = blockIdx.x * blockDim.x + threadIdx.x; i < n4; i += stride) {
        float4 v = w4[i];
        // |clip(w,-2,2)| == min(|w|,2)
        float s = fminf(fabsf(v.x), 2.0f) + fminf(fabsf(v.y), 2.0f) +
                  fminf(fabsf(v.z), 2.0f) + fminf(fabsf(v.w), 2.0f);
        acc += (double)s;
    }
    int lane = threadIdx.x & 63;
    int wid = threadIdx.x >> 6;
    #pragma unroll
    for (int off = 32; off > 0; off >>= 1) acc += __shfl_down(acc, off, 64);
    __shared__ double sred[4];
    if (lane == 0) sred[wid] = acc;
    __syncthreads();
    if (threadIdx.x == 0) atomicAdd(gsum, sred[0] + sred[1] + sred[2] + sred[3]);
}

// ---------------- quantize weight -> ternary f16 (exact in f16) ----------------

__global__ void quant_w(const float4* __restrict__ w4, half8* __restrict__ wq,
                        const double* __restrict__ gsum) {
    double gamma = fmax(*gsum * (1.0 / (double)NW_ELEMS), 1e-4);
    double rg = 1.0 / gamma;
    int i = blockIdx.x * blockDim.x + threadIdx.x;  // one half8 per thread, grid sized exactly
    float4 a = w4[2 * i];
    float4 b = w4[2 * i + 1];
    float vals[8] = {a.x, a.y, a.z, a.w, b.x, b.y, b.z, b.w};
    half8 q;
    #pragma unroll
    for (int j = 0; j < 8; j++) {
        float cv = fminf(fmaxf(vals[j], -2.0f), 2.0f);
        double t = rint((double)cv * rg);       // f64: matches the "true" gamma rounding
        t = fmax(-1.0, fmin(1.0, t));
        q[j] = (_Float16)t;
    }
    wq[i] = q;
}

// ---------------- convert x -> f16 ----------------

__global__ void cvt_x(const float4* __restrict__ x4, half8* __restrict__ x16) {
    int i = blockIdx.x * blockDim.x + threadIdx.x;
    float4 a = x4[2 * i];
    float4 b = x4[2 * i + 1];
    half8 h;
    h[0] = (_Float16)a.x; h[1] = (_Float16)a.y; h[2] = (_Float16)a.z; h[3] = (_Float16)a.w;
    h[4] = (_Float16)b.x; h[5] = (_Float16)b.y; h[6] = (_Float16)b.z; h[7] = (_Float16)b.w;
    x16[i] = h;
}

// ---------------- GEMM: out[m][n] = gamma * sum_k x16[m][k]*wq[n][k] + bias[n] ----------------
// m97 structure: 128x128 tile, BK=32, 4 waves (2x2), 4x4 16x16x32 frags per wave,
// global_load_lds width 16, single LDS buffer, 2 barriers per K-step.

#define TM 128
#define TN 128
#define TK 32

__device__ inline void gload_lds16(const void* g, void* l) {
    __builtin_amdgcn_global_load_lds(
        (const __attribute__((address_space(1))) void*)g,
        (__attribute__((address_space(3))) void*)l, 16, 0, 0);
}

__global__ __launch_bounds__(256) void gemm_kernel(
    const _Float16* __restrict__ A,   // x16 [M][K]
    const _Float16* __restrict__ B,   // wq  [N][K]
    const float* __restrict__ bias,   // [N]
    const double* __restrict__ gsum,
    float* __restrict__ out) {        // [M][N]
    __shared__ _Float16 sA[TM * TK];  // 8 KiB
    __shared__ _Float16 sB[TN * TK];  // 8 KiB

    const int tid = threadIdx.x;
    const int wid = tid >> 6;
    const int lane = tid & 63;
    const int wr = wid >> 1;          // wave row (0..1) -> 64 rows
    const int wc = wid & 1;           // wave col (0..1) -> 64 cols
    const int m0 = blockIdx.y * TM;
    const int n0 = blockIdx.x * TN;

    // staging: each issue = 4KB/block; wave wid covers rows [p*64 + wid*16, +16)
    const int sr = (wid << 4) + (lane >> 2);   // row within 64-row half
    const int sc = (lane & 3) << 3;            // k-offset in halves (16B chunks)
    const _Float16* gA0 = A + (size_t)(m0 + sr) * K_DIM + sc;
    const _Float16* gA1 = A + (size_t)(m0 + 64 + sr) * K_DIM + sc;
    const _Float16* gB0 = B + (size_t)(n0 + sr) * K_DIM + sc;
    const _Float16* gB1 = B + (size_t)(n0 + 64 + sr) * K_DIM + sc;
    _Float16* lA = &sA[wid << 9];   // wave-uniform base; HW adds lane*16B
    _Float16* lB = &sB[wid << 9];

    // fragment read offsets (A and B read along K: lane&15 = row, lane>>4 = k-group)
    const int fr = lane & 15;
    const int kg = lane >> 4;
    const int aoff = (wr * 64 + fr) * TK + kg * 8;
    const int boff = (wc * 64 + fr) * TK + kg * 8;

    f32x4 acc[4][4] = {};

    for (int k0 = 0; k0 < K_DIM; k0 += TK) {
        gload_lds16(gA0 + k0, lA);
        gload_lds16(gA1 + k0, lA + 2048);
        gload_lds16(gB0 + k0, lB);
        gload_lds16(gB1 + k0, lB + 2048);
        __syncthreads();   // drains vmcnt: LDS tiles ready

        half8 af[4], bf[4];
        #pragma unroll
        for (int i = 0; i < 4; i++) af[i] = *(const half8*)&sA[aoff + i * 16 * TK];
        #pragma unroll
        for (int i = 0; i < 4; i++) bf[i] = *(const half8*)&sB[boff + i * 16 * TK];
        #pragma unroll
        for (int mi = 0; mi < 4; mi++)
            #pragma unroll
            for (int ni = 0; ni < 4; ni++)
                acc[mi][ni] = __builtin_amdgcn_mfma_f32_16x16x32_f16(
                    af[mi], bf[ni], acc[mi][ni], 0, 0, 0);
        __syncthreads();   // compute done: safe to overwrite LDS
    }

    // epilogue: out = acc*gamma + bias. C/D layout: col=lane&15, row=(lane>>4)*4+j
    float gamma = (float)fmax(*gsum * (1.0 / (double)NW_ELEMS), 1e-4);
    float bv[4];
    #pragma unroll
    for (int ni = 0; ni < 4; ni++) bv[ni] = bias[n0 + wc * 64 + ni * 16 + fr];
    const int rbase = m0 + wr * 64 + (kg << 2);
    #pragma unroll
    for (int mi = 0; mi < 4; mi++) {
        #pragma unroll
        for (int ni = 0; ni < 4; ni++) {
            const int gn = n0 + wc * 64 + ni * 16 + fr;
            #pragma unroll
            for (int j = 0; j < 4; j++) {
                const int gm = rbase + mi * 16 + j;
                out[(size_t)gm * N_DIM + gn] = acc[mi][ni][j] * gamma + bv[ni];
            }
        }
    }
}

// ---------------- launch ----------------

extern "C" void kernel_launch(void* const* d_in, const int* in_sizes, int n_in,
                              void* d_out, int out_size, void* d_ws, size_t ws_size,
                              hipStream_t stream) {
    const float* x = (const float*)d_in[0];
    const float* w = (const float*)d_in[1];
    const float* bias = (const float*)d_in[2];
    float* out = (float*)d_out;

    char* ws = (char*)d_ws;
    double* gsum = (double*)ws;
    _Float16* x16 = (_Float16*)(ws + 256);
    _Float16* w16 = (_Float16*)(ws + 256 + (size_t)NX_ELEMS * 2);

    zero_gsum<<<1, 1, 0, stream>>>(gsum);
    gamma_reduce<<<2048, 256, 0, stream>>>((const float4*)w, gsum, NW_ELEMS / 4);
    quant_w<<<NW_ELEMS / 8 / 256, 256, 0, stream>>>((const float4*)w, (half8*)w16, gsum);
    cvt_x<<<NX_ELEMS / 8 / 256, 256, 0, stream>>>((const float4*)x, (half8*)x16);

    dim3 grid(N_DIM / TN, M_DIM / TM);
    gemm_kernel<<<grid, 256, 0, stream>>>(x16, w16, bias, gsum, out);
}

// Round 2
// 1168.210 us; speedup vs baseline: 1.1997x; 1.1997x over previous
//
#include <hip/hip_runtime.h>
#include <hip/hip_fp16.h>

// x[8192,4096] f32, w[16384,4096] f32, bias[16384] f32 -> out[8192,16384] f32
#define M_DIM 8192
#define K_DIM 4096
#define N_DIM 16384
#define NW_ELEMS (16384 * 4096)
#define NX_ELEMS (8192 * 4096)
#define NT 64   // K / 64

typedef _Float16 half8 __attribute__((ext_vector_type(8)));
typedef float f32x4 __attribute__((ext_vector_type(4)));

// ---------------- gamma = max(mean(|clip(w,-2,2)|), 1e-4), f64 accumulation ----------------

__global__ void zero_gsum(double* g) {
    if (threadIdx.x == 0 && blockIdx.x == 0) *g = 0.0;
}

__global__ void gamma_reduce(const float4* __restrict__ w4, double* __restrict__ gsum, int n4) {
    double acc = 0.0;
    int stride = gridDim.x * blockDim.x;
    for (int i = blockIdx.x * blockDim.x + threadIdx.x; i < n4; i += stride) {
        float4 v = w4[i];
        float s = fminf(fabsf(v.x), 2.0f) + fminf(fabsf(v.y), 2.0f) +
                  fminf(fabsf(v.z), 2.0f) + fminf(fabsf(v.w), 2.0f);
        acc += (double)s;
    }
    int lane = threadIdx.x & 63;
    int wid = threadIdx.x >> 6;
    #pragma unroll
    for (int off = 32; off > 0; off >>= 1) acc += __shfl_down(acc, off, 64);
    __shared__ double sred[4];
    if (lane == 0) sred[wid] = acc;
    __syncthreads();
    if (threadIdx.x == 0) atomicAdd(gsum, sred[0] + sred[1] + sred[2] + sred[3]);
}

// ---------------- quantize weight -> ternary f16 ----------------

__global__ void quant_w(const float4* __restrict__ w4, half8* __restrict__ wq,
                        const double* __restrict__ gsum) {
    double gamma = fmax(*gsum * (1.0 / (double)NW_ELEMS), 1e-4);
    double rg = 1.0 / gamma;
    int i = blockIdx.x * blockDim.x + threadIdx.x;
    float4 a = w4[2 * i];
    float4 b = w4[2 * i + 1];
    float vals[8] = {a.x, a.y, a.z, a.w, b.x, b.y, b.z, b.w};
    half8 q;
    #pragma unroll
    for (int j = 0; j < 8; j++) {
        float cv = fminf(fmaxf(vals[j], -2.0f), 2.0f);
        double t = rint((double)cv * rg);
        t = fmax(-1.0, fmin(1.0, t));
        q[j] = (_Float16)t;
    }
    wq[i] = q;
}

// ---------------- convert x -> f16 ----------------

__global__ void cvt_x(const float4* __restrict__ x4, half8* __restrict__ x16) {
    int i = blockIdx.x * blockDim.x + threadIdx.x;
    float4 a = x4[2 * i];
    float4 b = x4[2 * i + 1];
    half8 h;
    h[0] = (_Float16)a.x; h[1] = (_Float16)a.y; h[2] = (_Float16)a.z; h[3] = (_Float16)a.w;
    h[4] = (_Float16)b.x; h[5] = (_Float16)b.y; h[6] = (_Float16)b.z; h[7] = (_Float16)b.w;
    x16[i] = h;
}

// ---------------- 256x256 8-phase GEMM (T1+T2+T3+T4+T5) ----------------
// 512 threads = 8 waves (2M x 4N). Per wave: 128x64 output = acc[8][4] f32x4.
// LDS: 2 buffers x (A 256x64 + B 256x64) f16 = 128 KiB. XOR-swizzle slot^=(row&7).
// Per K-tile (BK=64): 4 phases x 16 MFMA; A staged p2, B staged p3 (into the
// READ buffer, for tile t+2 -- safe because A reads finish p1, B reads finish p1).
// Counted vmcnt(8) once per tile: leaves t+2's 8 loads in flight, t+1 resident.

__device__ inline void gload16(const _Float16* g, char* lds) {
    __builtin_amdgcn_global_load_lds((const __attribute__((address_space(1))) void*)g,
        (__attribute__((address_space(3))) void*)lds, 16, 0, 0);
}

#define MFMA16(a, b, c) __builtin_amdgcn_mfma_f32_16x16x32_f16(a, b, c, 0, 0, 0)

__global__ __launch_bounds__(512, 2) void gemm_kernel(
    const _Float16* __restrict__ A,   // x16 [M][K]
    const _Float16* __restrict__ B,   // wq  [N][K]
    const float* __restrict__ bias,
    const double* __restrict__ gsum,
    float* __restrict__ out) {
    __shared__ __align__(16) char sm[131072];

    const int tid = threadIdx.x;
    const int wid = tid >> 6;
    const int lane = tid & 63;
    const int fr = lane & 15;
    const int kg = lane >> 4;
    const int f7 = fr & 7;
    const int wm = wid >> 2;   // 0..1
    const int wn = wid & 3;    // 0..3

    // T1: bijective XCD swizzle (2048 blocks % 8 == 0). XCD x gets bm rows [4x,4x+4), all bn.
    const int orig = blockIdx.x;
    const int bm = ((orig & 7) << 2) + ((orig >> 3) & 3);
    const int bn = orig >> 5;
    const int m0 = bm << 8, n0 = bn << 8;

    // ---- staging addressing: linear LDS dest, inverse-swizzled global source ----
    // LDS byte o in a 32KB region: row = o>>7, slot = (o>>4)&7; holds global k-slot slot^(row&7).
    const int srow = tid >> 3;                       // 0..63
    const int ks8 = (((tid & 7) ^ (srow & 7)) << 3); // swizzled k element offset
    const int poff = srow * K_DIM + ks8;             // per-thread element offset
    const _Float16* Ab = A + (size_t)m0 * K_DIM;
    const _Float16* Bb = B + (size_t)n0 * K_DIM;
    const uint32_t dwave = (uint32_t)(wid << 10);    // wave-uniform LDS base part

    #define STAGE_A(kt, bufb) do {                                              \
        char* _base = sm + ((bufb) << 16);                                      \
        _Pragma("unroll")                                                       \
        for (int _i = 0; _i < 4; ++_i)                                          \
            gload16(Ab + (poff + _i * (64 * K_DIM) + (kt)),                     \
                    _base + (_i << 13) + dwave);                                \
    } while (0)
    #define STAGE_B(kt, bufb) do {                                              \
        char* _base = sm + ((bufb) << 16) + 32768;                              \
        _Pragma("unroll")                                                       \
        for (int _i = 0; _i < 4; ++_i)                                          \
            gload16(Bb + (poff + _i * (64 * K_DIM) + (kt)),                     \
                    _base + (_i << 13) + dwave);                                \
    } while (0)

    // ---- swizzled fragment reads (conflict-free: 8 lanes -> 8 distinct 16B slots) ----
    const char* smc = sm;
    #define RD_A(bufb, mf, s) \
        (*(const half8*)(smc + ((bufb) << 16) + (wm * 128 + (mf) * 16 + fr) * 128 + \
                         (((((s) << 2) | kg) ^ f7) << 4)))
    #define RD_B(bufb, nf, s) \
        (*(const half8*)(smc + ((bufb) << 16) + 32768 + (wn * 64 + (nf) * 16 + fr) * 128 + \
                         (((((s) << 2) | kg) ^ f7) << 4)))

    f32x4 acc[8][4] = {};
    half8 a0[4][2], a1[4][2], b0[2][2], b1[2][2];

    // prologue: tile 0 -> buf0, tile 1 -> buf1; wait tile 0 (leave tile 1's 8 in flight)
    STAGE_A(0, 0); STAGE_B(0, 0);
    STAGE_A(64, 1); STAGE_B(64, 1);
    asm volatile("s_waitcnt vmcnt(8)" ::: "memory");
    __builtin_amdgcn_s_barrier();

    for (int t = 0; t < NT; ++t) {
        const int cur = t & 1;
        const int kt2 = (t + 2) << 6;
        const bool st = (t < NT - 2);

        // ---- phase 0: read A lower-half + B lower-half; MFMA q0 ----
        #pragma unroll
        for (int i = 0; i < 4; ++i) { a0[i][0] = RD_A(cur, i, 0); a0[i][1] = RD_A(cur, i, 1); }
        #pragma unroll
        for (int j = 0; j < 2; ++j) { b0[j][0] = RD_B(cur, j, 0); b0[j][1] = RD_B(cur, j, 1); }
        __builtin_amdgcn_s_barrier();
        asm volatile("s_waitcnt lgkmcnt(0)" ::: "memory");
        __builtin_amdgcn_sched_barrier(0);
        __builtin_amdgcn_s_setprio(1);
        #pragma unroll
        for (int i = 0; i < 4; ++i)
            #pragma unroll
            for (int j = 0; j < 2; ++j) {
                acc[i][j] = MFMA16(a0[i][0], b0[j][0], acc[i][j]);
                acc[i][j] = MFMA16(a0[i][1], b0[j][1], acc[i][j]);
            }
        __builtin_amdgcn_s_setprio(0);
        __builtin_amdgcn_s_barrier();

        // ---- phase 1: read A upper-half + B upper-half; MFMA q1 ----
        #pragma unroll
        for (int i = 0; i < 4; ++i) { a1[i][0] = RD_A(cur, 4 + i, 0); a1[i][1] = RD_A(cur, 4 + i, 1); }
        #pragma unroll
        for (int j = 0; j < 2; ++j) { b1[j][0] = RD_B(cur, 2 + j, 0); b1[j][1] = RD_B(cur, 2 + j, 1); }
        __builtin_amdgcn_s_barrier();
        asm volatile("s_waitcnt lgkmcnt(0)" ::: "memory");
        __builtin_amdgcn_sched_barrier(0);
        __builtin_amdgcn_s_setprio(1);
        #pragma unroll
        for (int i = 0; i < 4; ++i)
            #pragma unroll
            for (int j = 0; j < 2; ++j) {
                acc[4 + i][j] = MFMA16(a1[i][0], b0[j][0], acc[4 + i][j]);
                acc[4 + i][j] = MFMA16(a1[i][1], b0[j][1], acc[4 + i][j]);
            }
        __builtin_amdgcn_s_setprio(0);
        __builtin_amdgcn_s_barrier();

        // ---- phase 2: stage A(t+2) into read buffer (A reads done at p1); MFMA q2 ----
        if (st) STAGE_A(kt2, cur);
        __builtin_amdgcn_s_barrier();
        __builtin_amdgcn_s_setprio(1);
        #pragma unroll
        for (int i = 0; i < 4; ++i)
            #pragma unroll
            for (int j = 0; j < 2; ++j) {
                acc[i][2 + j] = MFMA16(a0[i][0], b1[j][0], acc[i][2 + j]);
                acc[i][2 + j] = MFMA16(a0[i][1], b1[j][1], acc[i][2 + j]);
            }
        __builtin_amdgcn_s_setprio(0);
        __builtin_amdgcn_s_barrier();

        // ---- phase 3: stage B(t+2); MFMA q3; counted vmcnt ----
        if (st) STAGE_B(kt2, cur);
        __builtin_amdgcn_s_barrier();
        __builtin_amdgcn_s_setprio(1);
        #pragma unroll
        for (int i = 0; i < 4; ++i)
            #pragma unroll
            for (int j = 0; j < 2; ++j) {
                acc[4 + i][2 + j] = MFMA16(a1[i][0], b1[j][0], acc[4 + i][2 + j]);
                acc[4 + i][2 + j] = MFMA16(a1[i][1], b1[j][1], acc[4 + i][2 + j]);
            }
        __builtin_amdgcn_s_setprio(0);
        if (st) {
            asm volatile("s_waitcnt vmcnt(8)" ::: "memory");   // t+1 resident; t+2's 8 in flight
        } else if (t == NT - 2) {
            asm volatile("s_waitcnt vmcnt(0)" ::: "memory");   // drain: t+1 (= NT-1) resident
        }
        __builtin_amdgcn_s_barrier();
    }

    // ---- epilogue: out = acc*gamma + bias. C/D: col = fr, row = kg*4 + jj ----
    const float gamma = (float)fmax(*gsum * (1.0 / (double)NW_ELEMS), 1e-4);
    const int rbase = m0 + wm * 128 + (kg << 2);
    #pragma unroll
    for (int j = 0; j < 4; ++j) {
        const int gn = n0 + wn * 64 + j * 16 + fr;
        const float bv = bias[gn];
        #pragma unroll
        for (int i = 0; i < 8; ++i) {
            #pragma unroll
            for (int jj = 0; jj < 4; ++jj) {
                const int gm = rbase + i * 16 + jj;
                out[(size_t)gm * N_DIM + gn] = acc[i][j][jj] * gamma + bv;
            }
        }
    }
}

// ---------------- launch ----------------

extern "C" void kernel_launch(void* const* d_in, const int* in_sizes, int n_in,
                              void* d_out, int out_size, void* d_ws, size_t ws_size,
                              hipStream_t stream) {
    const float* x = (const float*)d_in[0];
    const float* w = (const float*)d_in[1];
    const float* bias = (const float*)d_in[2];
    float* out = (float*)d_out;

    char* ws = (char*)d_ws;
    double* gsum = (double*)ws;
    _Float16* x16 = (_Float16*)(ws + 256);
    _Float16* w16 = (_Float16*)(ws + 256 + (size_t)NX_ELEMS * 2);

    zero_gsum<<<1, 1, 0, stream>>>(gsum);
    gamma_reduce<<<2048, 256, 0, stream>>>((const float4*)w, gsum, NW_ELEMS / 4);
    quant_w<<<NW_ELEMS / 8 / 256, 256, 0, stream>>>((const float4*)w, (half8*)w16, gsum);
    cvt_x<<<NX_ELEMS / 8 / 256, 256, 0, stream>>>((const float4*)x, (half8*)x16);

    const int nblk = (M_DIM / 256) * (N_DIM / 256);   // 32 * 64 = 2048
    gemm_kernel<<<nblk, 512, 0, stream>>>(x16, w16, bias, gsum, out);
}

// Round 3
// 1041.139 us; speedup vs baseline: 1.3461x; 1.1220x over previous
//
#include <hip/hip_runtime.h>
#include <hip/hip_fp16.h>

// x[8192,4096] f32, w[16384,4096] f32, bias[16384] f32 -> out[8192,16384] f32
#define M_DIM 8192
#define K_DIM 4096
#define N_DIM 16384
#define NW_ELEMS (16384 * 4096)
#define NX_ELEMS (8192 * 4096)
#define NT 64   // K / 64

typedef _Float16 half8 __attribute__((ext_vector_type(8)));
typedef float f32x4 __attribute__((ext_vector_type(4)));

// ---------------- gamma = max(mean(|clip(w,-2,2)|), 1e-4), f64 accumulation ----------------

__global__ void zero_gsum(double* g) {
    if (threadIdx.x == 0 && blockIdx.x == 0) *g = 0.0;
}

__global__ void gamma_reduce(const float4* __restrict__ w4, double* __restrict__ gsum, int n4) {
    double acc = 0.0;
    int stride = gridDim.x * blockDim.x;
    for (int i = blockIdx.x * blockDim.x + threadIdx.x; i < n4; i += stride) {
        float4 v = w4[i];
        float s = fminf(fabsf(v.x), 2.0f) + fminf(fabsf(v.y), 2.0f) +
                  fminf(fabsf(v.z), 2.0f) + fminf(fabsf(v.w), 2.0f);
        acc += (double)s;
    }
    int lane = threadIdx.x & 63;
    int wid = threadIdx.x >> 6;
    #pragma unroll
    for (int off = 32; off > 0; off >>= 1) acc += __shfl_down(acc, off, 64);
    __shared__ double sred[4];
    if (lane == 0) sred[wid] = acc;
    __syncthreads();
    if (threadIdx.x == 0) atomicAdd(gsum, sred[0] + sred[1] + sred[2] + sred[3]);
}

// ---------------- quantize weight -> ternary f16 ----------------

__global__ void quant_w(const float4* __restrict__ w4, half8* __restrict__ wq,
                        const double* __restrict__ gsum) {
    double gamma = fmax(*gsum * (1.0 / (double)NW_ELEMS), 1e-4);
    double rg = 1.0 / gamma;
    int i = blockIdx.x * blockDim.x + threadIdx.x;
    float4 a = w4[2 * i];
    float4 b = w4[2 * i + 1];
    float vals[8] = {a.x, a.y, a.z, a.w, b.x, b.y, b.z, b.w};
    half8 q;
    #pragma unroll
    for (int j = 0; j < 8; j++) {
        float cv = fminf(fmaxf(vals[j], -2.0f), 2.0f);
        double t = rint((double)cv * rg);
        t = fmax(-1.0, fmin(1.0, t));
        q[j] = (_Float16)t;
    }
    wq[i] = q;
}

// ---------------- convert x -> f16 ----------------

__global__ void cvt_x(const float4* __restrict__ x4, half8* __restrict__ x16) {
    int i = blockIdx.x * blockDim.x + threadIdx.x;
    float4 a = x4[2 * i];
    float4 b = x4[2 * i + 1];
    half8 h;
    h[0] = (_Float16)a.x; h[1] = (_Float16)a.y; h[2] = (_Float16)a.z; h[3] = (_Float16)a.w;
    h[4] = (_Float16)b.x; h[5] = (_Float16)b.y; h[6] = (_Float16)b.z; h[7] = (_Float16)b.w;
    x16[i] = h;
}

// ---------------- 256x256 GEMM, pipelined reads + 2 barriers/K-tile ----------------
// 512 threads = 8 waves (2M x 4N). Per wave: 128x64 output = acc[8][4] f32x4.
// LDS: 2 buffers x (A 256x64 + B 256x64) f16 = 128 KiB. XOR-swizzle slot^=(row&7).
// Per K-tile: quadrants q0..q3 of 16 MFMA; fragment reads issued ONE phase ahead
// (a1 before q0, b1 before q1, next tile's a0/b0 after end-of-tile barrier) so the
// LDS pipe runs under the MFMA pipe in-wave. Only 2 barriers per tile:
//   B1: lgkmcnt(0)+barrier before staging t+2 into the read buffer
//   B2: counted vmcnt(8)+barrier at tile end (t+1 resident, t+2's 8 in flight)

__device__ inline void gload16(const _Float16* g, char* lds) {
    __builtin_amdgcn_global_load_lds((const __attribute__((address_space(1))) void*)g,
        (__attribute__((address_space(3))) void*)lds, 16, 0, 0);
}

#define MFMA16(a, b, c) __builtin_amdgcn_mfma_f32_16x16x32_f16(a, b, c, 0, 0, 0)

__global__ __launch_bounds__(512, 2) void gemm_kernel(
    const _Float16* __restrict__ A,   // x16 [M][K]
    const _Float16* __restrict__ B,   // wq  [N][K]
    const float* __restrict__ bias,
    const double* __restrict__ gsum,
    float* __restrict__ out) {
    __shared__ __align__(16) char sm[131072];

    const int tid = threadIdx.x;
    const int wid = tid >> 6;
    const int lane = tid & 63;
    const int fr = lane & 15;
    const int kg = lane >> 4;
    const int f7 = fr & 7;
    const int wm = wid >> 2;   // 0..1
    const int wn = wid & 3;    // 0..3

    // T1: bijective XCD swizzle (2048 % 8 == 0).
    const int orig = blockIdx.x;
    const int bm = ((orig & 7) << 2) + ((orig >> 3) & 3);
    const int bn = orig >> 5;
    const int m0 = bm << 8, n0 = bn << 8;

    // staging: linear LDS dest, inverse-swizzled global source (rule #21)
    const int srow = tid >> 3;
    const int ks8 = (((tid & 7) ^ (srow & 7)) << 3);
    const int poff = srow * K_DIM + ks8;
    const _Float16* Ab = A + (size_t)m0 * K_DIM;
    const _Float16* Bb = B + (size_t)n0 * K_DIM;
    const uint32_t dwave = (uint32_t)(wid << 10);

    #define STAGE_A(kt, bufb) do {                                              \
        char* _base = sm + ((bufb) << 16);                                      \
        _Pragma("unroll")                                                       \
        for (int _i = 0; _i < 4; ++_i)                                          \
            gload16(Ab + (poff + _i * (64 * K_DIM) + (kt)),                     \
                    _base + (_i << 13) + dwave);                                \
    } while (0)
    #define STAGE_B(kt, bufb) do {                                              \
        char* _base = sm + ((bufb) << 16) + 32768;                              \
        _Pragma("unroll")                                                       \
        for (int _i = 0; _i < 4; ++_i)                                          \
            gload16(Bb + (poff + _i * (64 * K_DIM) + (kt)),                     \
                    _base + (_i << 13) + dwave);                                \
    } while (0)

    // swizzled fragment reads (conflict-free)
    const char* smc = sm;
    #define RD_A(bufb, mf, s) \
        (*(const half8*)(smc + ((bufb) << 16) + (wm * 128 + (mf) * 16 + fr) * 128 + \
                         (((((s) << 2) | kg) ^ f7) << 4)))
    #define RD_B(bufb, nf, s) \
        (*(const half8*)(smc + ((bufb) << 16) + 32768 + (wn * 64 + (nf) * 16 + fr) * 128 + \
                         (((((s) << 2) | kg) ^ f7) << 4)))

    f32x4 acc[8][4] = {};
    half8 a0[4][2], a1[4][2], b0[2][2], b1[2][2];

    // prologue: tile 0 -> buf0, tile 1 -> buf1; wait tile 0
    STAGE_A(0, 0); STAGE_B(0, 0);
    STAGE_A(64, 1); STAGE_B(64, 1);
    asm volatile("s_waitcnt vmcnt(8)" ::: "memory");
    __builtin_amdgcn_s_barrier();
    asm volatile("" ::: "memory");
    __builtin_amdgcn_sched_barrier(0);

    // prime tile-0 a0/b0 reads
    #pragma unroll
    for (int i = 0; i < 4; ++i) { a0[i][0] = RD_A(0, i, 0); a0[i][1] = RD_A(0, i, 1); }
    #pragma unroll
    for (int j = 0; j < 2; ++j) { b0[j][0] = RD_B(0, j, 0); b0[j][1] = RD_B(0, j, 1); }

    for (int t = 0; t < NT; ++t) {
        const int cur = t & 1;
        const int kt2 = (t + 2) << 6;
        const bool st = (t < NT - 2);

        // ---- q0 (a0,b0); prefetch a1 ----
        #pragma unroll
        for (int i = 0; i < 4; ++i) { a1[i][0] = RD_A(cur, 4 + i, 0); a1[i][1] = RD_A(cur, 4 + i, 1); }
        __builtin_amdgcn_s_setprio(1);
        #pragma unroll
        for (int i = 0; i < 4; ++i)
            #pragma unroll
            for (int j = 0; j < 2; ++j) {
                acc[i][j] = MFMA16(a0[i][0], b0[j][0], acc[i][j]);
                acc[i][j] = MFMA16(a0[i][1], b0[j][1], acc[i][j]);
            }
        __builtin_amdgcn_s_setprio(0);

        // ---- q1 (a1,b0); prefetch b1 ----
        #pragma unroll
        for (int j = 0; j < 2; ++j) { b1[j][0] = RD_B(cur, 2 + j, 0); b1[j][1] = RD_B(cur, 2 + j, 1); }
        __builtin_amdgcn_s_setprio(1);
        #pragma unroll
        for (int i = 0; i < 4; ++i)
            #pragma unroll
            for (int j = 0; j < 2; ++j) {
                acc[4 + i][j] = MFMA16(a1[i][0], b0[j][0], acc[4 + i][j]);
                acc[4 + i][j] = MFMA16(a1[i][1], b0[j][1], acc[4 + i][j]);
            }
        __builtin_amdgcn_s_setprio(0);

        // ---- B1: all waves finished reading buf[cur] -> safe to stage into it ----
        asm volatile("s_waitcnt lgkmcnt(0)" ::: "memory");
        __builtin_amdgcn_sched_barrier(0);
        __builtin_amdgcn_s_barrier();
        asm volatile("" ::: "memory");
        __builtin_amdgcn_sched_barrier(0);

        // ---- q2 (a0,b1); stage A(t+2) into read buffer ----
        if (st) STAGE_A(kt2, cur);
        __builtin_amdgcn_s_setprio(1);
        #pragma unroll
        for (int i = 0; i < 4; ++i)
            #pragma unroll
            for (int j = 0; j < 2; ++j) {
                acc[i][2 + j] = MFMA16(a0[i][0], b1[j][0], acc[i][2 + j]);
                acc[i][2 + j] = MFMA16(a0[i][1], b1[j][1], acc[i][2 + j]);
            }
        __builtin_amdgcn_s_setprio(0);

        // ---- q3 (a1,b1); stage B(t+2) ----
        if (st) STAGE_B(kt2, cur);
        __builtin_amdgcn_s_setprio(1);
        #pragma unroll
        for (int i = 0; i < 4; ++i)
            #pragma unroll
            for (int j = 0; j < 2; ++j) {
                acc[4 + i][2 + j] = MFMA16(a1[i][0], b1[j][0], acc[4 + i][2 + j]);
                acc[4 + i][2 + j] = MFMA16(a1[i][1], b1[j][1], acc[4 + i][2 + j]);
            }
        __builtin_amdgcn_s_setprio(0);

        // ---- B2: counted vmcnt; tile t+1 resident for everyone ----
        if (st) {
            asm volatile("s_waitcnt vmcnt(8)" ::: "memory");
        } else if (t == NT - 2) {
            asm volatile("s_waitcnt vmcnt(0)" ::: "memory");
        }
        __builtin_amdgcn_sched_barrier(0);
        __builtin_amdgcn_s_barrier();
        asm volatile("" ::: "memory");
        __builtin_amdgcn_sched_barrier(0);

        // ---- prime next tile's a0/b0 (overlaps next q0's lgkm wait) ----
        if (t < NT - 1) {
            const int nxt = (t + 1) & 1;
            #pragma unroll
            for (int i = 0; i < 4; ++i) { a0[i][0] = RD_A(nxt, i, 0); a0[i][1] = RD_A(nxt, i, 1); }
            #pragma unroll
            for (int j = 0; j < 2; ++j) { b0[j][0] = RD_B(nxt, j, 0); b0[j][1] = RD_B(nxt, j, 1); }
        }
    }

    // ---- epilogue: out = acc*gamma + bias. C/D: col = fr, row = kg*4 + jj ----
    const float gamma = (float)fmax(*gsum * (1.0 / (double)NW_ELEMS), 1e-4);
    const int rbase = m0 + wm * 128 + (kg << 2);
    #pragma unroll
    for (int j = 0; j < 4; ++j) {
        const int gn = n0 + wn * 64 + j * 16 + fr;
        const float bv = bias[gn];
        #pragma unroll
        for (int i = 0; i < 8; ++i) {
            #pragma unroll
            for (int jj = 0; jj < 4; ++jj) {
                const int gm = rbase + i * 16 + jj;
                out[(size_t)gm * N_DIM + gn] = acc[i][j][jj] * gamma + bv;
            }
        }
    }
}

// ---------------- launch ----------------

extern "C" void kernel_launch(void* const* d_in, const int* in_sizes, int n_in,
                              void* d_out, int out_size, void* d_ws, size_t ws_size,
                              hipStream_t stream) {
    const float* x = (const float*)d_in[0];
    const float* w = (const float*)d_in[1];
    const float* bias = (const float*)d_in[2];
    float* out = (float*)d_out;

    char* ws = (char*)d_ws;
    double* gsum = (double*)ws;
    _Float16* x16 = (_Float16*)(ws + 256);
    _Float16* w16 = (_Float16*)(ws + 256 + (size_t)NX_ELEMS * 2);

    zero_gsum<<<1, 1, 0, stream>>>(gsum);
    gamma_reduce<<<2048, 256, 0, stream>>>((const float4*)w, gsum, NW_ELEMS / 4);
    quant_w<<<NW_ELEMS / 8 / 256, 256, 0, stream>>>((const float4*)w, (half8*)w16, gsum);
    cvt_x<<<NX_ELEMS / 8 / 256, 256, 0, stream>>>((const float4*)x, (half8*)x16);

    const int nblk = (M_DIM / 256) * (N_DIM / 256);   // 2048
    gemm_kernel<<<nblk, 512, 0, stream>>>(x16, w16, bias, gsum, out);
}

// Round 4
// 1036.741 us; speedup vs baseline: 1.3518x; 1.0042x over previous
//
#include <hip/hip_runtime.h>
#include <hip/hip_fp16.h>

// x[8192,4096] f32, w[16384,4096] f32, bias[16384] f32 -> out[8192,16384] f32
#define M_DIM 8192
#define K_DIM 4096
#define N_DIM 16384
#define NW_ELEMS (16384 * 4096)
#define NX_ELEMS (8192 * 4096)
#define NT 64   // K / 64

typedef _Float16 half8 __attribute__((ext_vector_type(8)));
typedef float f32x4 __attribute__((ext_vector_type(4)));

// ---------------- gamma = max(mean(|clip(w,-2,2)|), 1e-4), f64 accumulation ----------------

__global__ void zero_gsum(double* g) {
    if (threadIdx.x == 0 && blockIdx.x == 0) *g = 0.0;
}

__global__ void gamma_reduce(const float4* __restrict__ w4, double* __restrict__ gsum, int n4) {
    double acc = 0.0;
    int stride = gridDim.x * blockDim.x;
    for (int i = blockIdx.x * blockDim.x + threadIdx.x; i < n4; i += stride) {
        float4 v = w4[i];
        float s = fminf(fabsf(v.x), 2.0f) + fminf(fabsf(v.y), 2.0f) +
                  fminf(fabsf(v.z), 2.0f) + fminf(fabsf(v.w), 2.0f);
        acc += (double)s;
    }
    int lane = threadIdx.x & 63;
    int wid = threadIdx.x >> 6;
    #pragma unroll
    for (int off = 32; off > 0; off >>= 1) acc += __shfl_down(acc, off, 64);
    __shared__ double sred[4];
    if (lane == 0) sred[wid] = acc;
    __syncthreads();
    if (threadIdx.x == 0) atomicAdd(gsum, sred[0] + sred[1] + sred[2] + sred[3]);
}

// ---------------- quantize weight -> ternary f16 ----------------

__global__ void quant_w(const float4* __restrict__ w4, half8* __restrict__ wq,
                        const double* __restrict__ gsum) {
    double gamma = fmax(*gsum * (1.0 / (double)NW_ELEMS), 1e-4);
    double rg = 1.0 / gamma;
    int i = blockIdx.x * blockDim.x + threadIdx.x;
    float4 a = w4[2 * i];
    float4 b = w4[2 * i + 1];
    float vals[8] = {a.x, a.y, a.z, a.w, b.x, b.y, b.z, b.w};
    half8 q;
    #pragma unroll
    for (int j = 0; j < 8; j++) {
        float cv = fminf(fmaxf(vals[j], -2.0f), 2.0f);
        double t = rint((double)cv * rg);
        t = fmax(-1.0, fmin(1.0, t));
        q[j] = (_Float16)t;
    }
    wq[i] = q;
}

// ---------------- convert x -> f16 ----------------

__global__ void cvt_x(const float4* __restrict__ x4, half8* __restrict__ x16) {
    int i = blockIdx.x * blockDim.x + threadIdx.x;
    float4 a = x4[2 * i];
    float4 b = x4[2 * i + 1];
    half8 h;
    h[0] = (_Float16)a.x; h[1] = (_Float16)a.y; h[2] = (_Float16)a.z; h[3] = (_Float16)a.w;
    h[4] = (_Float16)b.x; h[5] = (_Float16)b.y; h[6] = (_Float16)b.z; h[7] = (_Float16)b.w;
    x16[i] = h;
}

// ---------------- 256x256 GEMM, read-balanced 2-window pipeline ----------------
// 512 threads = 8 waves (2M x 4N). Per wave: 128x64 output = acc[8][4] f32x4.
// LDS: 2 x (A 256x64 + B 256x64) f16 = 128 KiB. XOR-swizzle slot^=(row&7), conflict-free.
// Window1 (B2->B1): read a1,b1 [buf cur]; MFMA a0xb0, a0xb1  -> a0 DEAD at B1.
// Window2 (B1->B2): stage A(t+2); read a0-next [buf nxt, resident via vmcnt(4)@B1,
//                   reuses a0 regs]; MFMA a1xb0; stage B(t+2); MFMA a1xb1.
// Tail: vmcnt(8) -> B(t+1) resident -> read b0-next before the barrier.
// Register budget unchanged (a0/a1/b0/b1 + acc = 224; 2 waves/SIMD preserved).

__device__ inline void gload16(const _Float16* g, char* lds) {
    __builtin_amdgcn_global_load_lds((const __attribute__((address_space(1))) void*)g,
        (__attribute__((address_space(3))) void*)lds, 16, 0, 0);
}

#define MFMA16(a, b, c) __builtin_amdgcn_mfma_f32_16x16x32_f16(a, b, c, 0, 0, 0)

__global__ __launch_bounds__(512, 2) void gemm_kernel(
    const _Float16* __restrict__ A,   // x16 [M][K]
    const _Float16* __restrict__ B,   // wq  [N][K]
    const float* __restrict__ bias,
    const double* __restrict__ gsum,
    float* __restrict__ out) {
    __shared__ __align__(16) char sm[131072];

    const int tid = threadIdx.x;
    const int wid = tid >> 6;
    const int lane = tid & 63;
    const int fr = lane & 15;
    const int kg = lane >> 4;
    const int f7 = fr & 7;
    const int wm = wid >> 2;   // 0..1
    const int wn = wid & 3;    // 0..3

    // T1: bijective XCD swizzle (2048 % 8 == 0).
    const int orig = blockIdx.x;
    const int bm = ((orig & 7) << 2) + ((orig >> 3) & 3);
    const int bn = orig >> 5;
    const int m0 = bm << 8, n0 = bn << 8;

    // staging: linear LDS dest, inverse-swizzled global source (rule #21)
    const int srow = tid >> 3;
    const int ks8 = (((tid & 7) ^ (srow & 7)) << 3);
    const int poff = srow * K_DIM + ks8;
    const _Float16* Ab = A + (size_t)m0 * K_DIM;
    const _Float16* Bb = B + (size_t)n0 * K_DIM;
    const uint32_t dwave = (uint32_t)(wid << 10);

    #define STAGE_A(kt, bufb) do {                                              \
        char* _base = sm + ((bufb) << 16);                                      \
        _Pragma("unroll")                                                       \
        for (int _i = 0; _i < 4; ++_i)                                          \
            gload16(Ab + (poff + _i * (64 * K_DIM) + (kt)),                     \
                    _base + (_i << 13) + dwave);                                \
    } while (0)
    #define STAGE_B(kt, bufb) do {                                              \
        char* _base = sm + ((bufb) << 16) + 32768;                              \
        _Pragma("unroll")                                                       \
        for (int _i = 0; _i < 4; ++_i)                                          \
            gload16(Bb + (poff + _i * (64 * K_DIM) + (kt)),                     \
                    _base + (_i << 13) + dwave);                                \
    } while (0)

    // swizzled fragment reads (conflict-free)
    const char* smc = sm;
    #define RD_A(bufb, mf, s) \
        (*(const half8*)(smc + ((bufb) << 16) + (wm * 128 + (mf) * 16 + fr) * 128 + \
                         (((((s) << 2) | kg) ^ f7) << 4)))
    #define RD_B(bufb, nf, s) \
        (*(const half8*)(smc + ((bufb) << 16) + 32768 + (wn * 64 + (nf) * 16 + fr) * 128 + \
                         (((((s) << 2) | kg) ^ f7) << 4)))

    f32x4 acc[8][4] = {};
    half8 a0[4][2], a1[4][2], b0[2][2], b1[2][2];

    // prologue: tile 0 -> buf0, tile 1 -> buf1; wait tile 0; prime a0,b0 of tile 0
    STAGE_A(0, 0); STAGE_B(0, 0);
    STAGE_A(64, 1); STAGE_B(64, 1);
    asm volatile("s_waitcnt vmcnt(8)" ::: "memory");
    __builtin_amdgcn_s_barrier();
    asm volatile("" ::: "memory");
    __builtin_amdgcn_sched_barrier(0);
    #pragma unroll
    for (int i = 0; i < 4; ++i) { a0[i][0] = RD_A(0, i, 0); a0[i][1] = RD_A(0, i, 1); }
    #pragma unroll
    for (int j = 0; j < 2; ++j) { b0[j][0] = RD_B(0, j, 0); b0[j][1] = RD_B(0, j, 1); }

    for (int t = 0; t < NT; ++t) {
        const int cur = t & 1;
        const int nxt = cur ^ 1;
        const int kt2 = (t + 2) << 6;
        const bool st = (t < NT - 2);
        const bool rd = (t < NT - 1);

        // ==== window 1: reads a1,b1 from buf[cur]; MFMA a0 x {b0, b1} ====
        #pragma unroll
        for (int i = 0; i < 4; ++i) { a1[i][0] = RD_A(cur, 4 + i, 0); a1[i][1] = RD_A(cur, 4 + i, 1); }
        __builtin_amdgcn_s_setprio(1);
        #pragma unroll
        for (int i = 0; i < 4; ++i)
            #pragma unroll
            for (int j = 0; j < 2; ++j) {
                acc[i][j] = MFMA16(a0[i][0], b0[j][0], acc[i][j]);
                acc[i][j] = MFMA16(a0[i][1], b0[j][1], acc[i][j]);
            }
        __builtin_amdgcn_s_setprio(0);
        #pragma unroll
        for (int j = 0; j < 2; ++j) { b1[j][0] = RD_B(cur, 2 + j, 0); b1[j][1] = RD_B(cur, 2 + j, 1); }
        __builtin_amdgcn_s_setprio(1);
        #pragma unroll
        for (int i = 0; i < 4; ++i)
            #pragma unroll
            for (int j = 0; j < 2; ++j) {
                acc[i][2 + j] = MFMA16(a0[i][0], b1[j][0], acc[i][2 + j]);
                acc[i][2 + j] = MFMA16(a0[i][1], b1[j][1], acc[i][2 + j]);
            }
        __builtin_amdgcn_s_setprio(0);

        // ==== B1: buf[cur] reads done; A(t+1) resident (4 oldest loads) ====
        asm volatile("s_waitcnt vmcnt(4) lgkmcnt(0)" ::: "memory");
        __builtin_amdgcn_sched_barrier(0);
        __builtin_amdgcn_s_barrier();
        asm volatile("" ::: "memory");
        __builtin_amdgcn_sched_barrier(0);

        // ==== window 2: stage A(t+2); re-read a0 <- next tile; MFMA a1 x {b0, b1} ====
        if (st) STAGE_A(kt2, cur);
        if (rd) {
            #pragma unroll
            for (int i = 0; i < 4; ++i) { a0[i][0] = RD_A(nxt, i, 0); a0[i][1] = RD_A(nxt, i, 1); }
        }
        __builtin_amdgcn_s_setprio(1);
        #pragma unroll
        for (int i = 0; i < 4; ++i)
            #pragma unroll
            for (int j = 0; j < 2; ++j) {
                acc[4 + i][j] = MFMA16(a1[i][0], b0[j][0], acc[4 + i][j]);
                acc[4 + i][j] = MFMA16(a1[i][1], b0[j][1], acc[4 + i][j]);
            }
        __builtin_amdgcn_s_setprio(0);
        if (st) STAGE_B(kt2, cur);
        __builtin_amdgcn_s_setprio(1);
        #pragma unroll
        for (int i = 0; i < 4; ++i)
            #pragma unroll
            for (int j = 0; j < 2; ++j) {
                acc[4 + i][2 + j] = MFMA16(a1[i][0], b1[j][0], acc[4 + i][2 + j]);
                acc[4 + i][2 + j] = MFMA16(a1[i][1], b1[j][1], acc[4 + i][2 + j]);
            }
        __builtin_amdgcn_s_setprio(0);

        // ==== B2: B(t+1) resident; read b0-next between wait and barrier ====
        if (st) {
            asm volatile("s_waitcnt vmcnt(8)" ::: "memory");
        } else if (t == NT - 2) {
            asm volatile("s_waitcnt vmcnt(0)" ::: "memory");
        }
        __builtin_amdgcn_sched_barrier(0);
        if (rd) {
            #pragma unroll
            for (int j = 0; j < 2; ++j) { b0[j][0] = RD_B(nxt, j, 0); b0[j][1] = RD_B(nxt, j, 1); }
        }
        __builtin_amdgcn_sched_barrier(0);
        __builtin_amdgcn_s_barrier();
        asm volatile("" ::: "memory");
        __builtin_amdgcn_sched_barrier(0);
    }

    // ---- epilogue: out = acc*gamma + bias. C/D: col = fr, row = kg*4 + jj ----
    const float gamma = (float)fmax(*gsum * (1.0 / (double)NW_ELEMS), 1e-4);
    const int rbase = m0 + wm * 128 + (kg << 2);
    #pragma unroll
    for (int j = 0; j < 4; ++j) {
        const int gn = n0 + wn * 64 + j * 16 + fr;
        const float bv = bias[gn];
        #pragma unroll
        for (int i = 0; i < 8; ++i) {
            #pragma unroll
            for (int jj = 0; jj < 4; ++jj) {
                const int gm = rbase + i * 16 + jj;
                out[(size_t)gm * N_DIM + gn] = acc[i][j][jj] * gamma + bv;
            }
        }
    }
}

// ---------------- launch ----------------

extern "C" void kernel_launch(void* const* d_in, const int* in_sizes, int n_in,
                              void* d_out, int out_size, void* d_ws, size_t ws_size,
                              hipStream_t stream) {
    const float* x = (const float*)d_in[0];
    const float* w = (const float*)d_in[1];
    const float* bias = (const float*)d_in[2];
    float* out = (float*)d_out;

    char* ws = (char*)d_ws;
    double* gsum = (double*)ws;
    _Float16* x16 = (_Float16*)(ws + 256);
    _Float16* w16 = (_Float16*)(ws + 256 + (size_t)NX_ELEMS * 2);

    zero_gsum<<<1, 1, 0, stream>>>(gsum);
    gamma_reduce<<<2048, 256, 0, stream>>>((const float4*)w, gsum, NW_ELEMS / 4);
    quant_w<<<NW_ELEMS / 8 / 256, 256, 0, stream>>>((const float4*)w, (half8*)w16, gsum);
    cvt_x<<<NX_ELEMS / 8 / 256, 256, 0, stream>>>((const float4*)x, (half8*)x16);

    const int nblk = (M_DIM / 256) * (N_DIM / 256);   // 2048
    gemm_kernel<<<nblk, 512, 0, stream>>>(x16, w16, bias, gsum, out);
}

// Round 5
// 1018.447 us; speedup vs baseline: 1.3761x; 1.0180x over previous
//
#include <hip/hip_runtime.h>
#include <hip/hip_fp16.h>

// x[8192,4096] f32, w[16384,4096] f32, bias[16384] f32 -> out[8192,16384] f32
#define M_DIM 8192
#define K_DIM 4096
#define N_DIM 16384
#define NW_ELEMS (16384 * 4096)
#define NX_ELEMS (8192 * 4096)
#define NT 64   // K / 64

typedef _Float16 half8 __attribute__((ext_vector_type(8)));
typedef float f32x4 __attribute__((ext_vector_type(4)));

// ---------------- gamma = max(mean(|clip(w,-2,2)|), 1e-4), f64 accumulation ----------------

__global__ void zero_gsum(double* g) {
    if (threadIdx.x == 0 && blockIdx.x == 0) *g = 0.0;
}

__global__ void gamma_reduce(const float4* __restrict__ w4, double* __restrict__ gsum, int n4) {
    double acc = 0.0;
    int stride = gridDim.x * blockDim.x;
    for (int i = blockIdx.x * blockDim.x + threadIdx.x; i < n4; i += stride) {
        float4 v = w4[i];
        float s = fminf(fabsf(v.x), 2.0f) + fminf(fabsf(v.y), 2.0f) +
                  fminf(fabsf(v.z), 2.0f) + fminf(fabsf(v.w), 2.0f);
        acc += (double)s;
    }
    int lane = threadIdx.x & 63;
    int wid = threadIdx.x >> 6;
    #pragma unroll
    for (int off = 32; off > 0; off >>= 1) acc += __shfl_down(acc, off, 64);
    __shared__ double sred[4];
    if (lane == 0) sred[wid] = acc;
    __syncthreads();
    if (threadIdx.x == 0) atomicAdd(gsum, sred[0] + sred[1] + sred[2] + sred[3]);
}

// ---------------- quantize weight -> ternary f16 ----------------

__global__ void quant_w(const float4* __restrict__ w4, half8* __restrict__ wq,
                        const double* __restrict__ gsum) {
    double gamma = fmax(*gsum * (1.0 / (double)NW_ELEMS), 1e-4);
    double rg = 1.0 / gamma;
    int i = blockIdx.x * blockDim.x + threadIdx.x;
    float4 a = w4[2 * i];
    float4 b = w4[2 * i + 1];
    float vals[8] = {a.x, a.y, a.z, a.w, b.x, b.y, b.z, b.w};
    half8 q;
    #pragma unroll
    for (int j = 0; j < 8; j++) {
        float cv = fminf(fmaxf(vals[j], -2.0f), 2.0f);
        double t = rint((double)cv * rg);
        t = fmax(-1.0, fmin(1.0, t));
        q[j] = (_Float16)t;
    }
    wq[i] = q;
}

// ---------------- convert x -> f16 ----------------

__global__ void cvt_x(const float4* __restrict__ x4, half8* __restrict__ x16) {
    int i = blockIdx.x * blockDim.x + threadIdx.x;
    float4 a = x4[2 * i];
    float4 b = x4[2 * i + 1];
    half8 h;
    h[0] = (_Float16)a.x; h[1] = (_Float16)a.y; h[2] = (_Float16)a.z; h[3] = (_Float16)a.w;
    h[4] = (_Float16)b.x; h[5] = (_Float16)b.y; h[6] = (_Float16)b.z; h[7] = (_Float16)b.w;
    x16[i] = h;
}

// ---------------- 256x256 GEMM, base-ptr addressing + 2 barriers/K-tile ----------------
// 512 threads = 8 waves (2M x 4N). Per wave: 128x64 output = acc[8][4] f32x4.
// LDS layout: A buf0 @0, A buf1 @32768, B buf0 @65536, B buf1 @98304 (128 KiB).
// XOR-swizzle slot^=(row&7) -> conflict-free ds_read_b128.
// All fragment reads: 4 precomputed base pointers (pA0/pA1/pB0/pB1 carry the
// lane-dependent swizzle) + compile-time immediate (buf*32768 + frag*2048 < 64K).
// Loop unrolled x2 so the buffer index is STATIC (rule #20).
// Per tile: win1 {read b0,a1; MFMA a0xb0; read b1; MFMA a0xb1}
//           B1 = vmcnt(4)+lgkmcnt(0)+barrier  (A(t+1) resident for ALL waves)
//           win2 {stage A(t+2); prefetch a0<-nxt; MFMA a1xb0; stage B(t+2); MFMA a1xb1}
//           B2 = vmcnt(8)+barrier             (B(t+1) resident for ALL waves)
// b0 is read AFTER B2's barrier (win1 head of next tile) -- no cross-wave race.

__device__ inline void gload16(const _Float16* g, char* lds) {
    __builtin_amdgcn_global_load_lds((const __attribute__((address_space(1))) void*)g,
        (__attribute__((address_space(3))) void*)lds, 16, 0, 0);
}

#define MFMA16(a, b, c) __builtin_amdgcn_mfma_f32_16x16x32_f16(a, b, c, 0, 0, 0)

__global__ __launch_bounds__(512, 2) void gemm_kernel(
    const _Float16* __restrict__ A,   // x16 [M][K]
    const _Float16* __restrict__ B,   // wq  [N][K]
    const float* __restrict__ bias,
    const double* __restrict__ gsum,
    float* __restrict__ out) {
    __shared__ __align__(16) char sm[131072];

    const int tid = threadIdx.x;
    const int wid = tid >> 6;
    const int lane = tid & 63;
    const int fr = lane & 15;
    const int kg = lane >> 4;
    const int f7 = fr & 7;
    const int wm = wid >> 2;   // 0..1
    const int wn = wid & 3;    // 0..3

    // T1: bijective XCD swizzle (2048 % 8 == 0).
    const int orig = blockIdx.x;
    const int bm = ((orig & 7) << 2) + ((orig >> 3) & 3);
    const int bn = orig >> 5;
    const int m0 = bm << 8, n0 = bn << 8;

    // staging: linear LDS dest, inverse-swizzled global source (rule #21)
    const int srow = tid >> 3;
    const int ks8 = (((tid & 7) ^ (srow & 7)) << 3);
    const int poff = srow * K_DIM + ks8;
    const _Float16* Ab = A + (size_t)m0 * K_DIM + poff;
    const _Float16* Bb = B + (size_t)n0 * K_DIM + poff;
    const uint32_t dwave = (uint32_t)(wid << 10);

    #define STAGE_A(kt, bufb) do {                                              \
        _Pragma("unroll")                                                       \
        for (int _i = 0; _i < 4; ++_i)                                          \
            gload16(Ab + (_i * (64 * K_DIM) + (kt)),                            \
                    sm + (bufb) * 32768 + (_i << 13) + dwave);                  \
    } while (0)
    #define STAGE_B(kt, bufb) do {                                              \
        _Pragma("unroll")                                                       \
        for (int _i = 0; _i < 4; ++_i)                                          \
            gload16(Bb + (_i * (64 * K_DIM) + (kt)),                            \
                    sm + 65536 + (bufb) * 32768 + (_i << 13) + dwave);          \
    } while (0)

    // base pointers carrying the lane-dependent swizzle; all reads = base + imm
    const char* const smc = sm;
    const char* const pA0 = smc + ((wm * 128 + fr) << 7) + ((kg ^ f7) << 4);
    const char* const pA1 = smc + ((wm * 128 + fr) << 7) + (((4 | kg) ^ f7) << 4);
    const char* const pB0 = smc + 65536 + ((wn * 64 + fr) << 7) + ((kg ^ f7) << 4);
    const char* const pB1 = smc + 65536 + ((wn * 64 + fr) << 7) + (((4 | kg) ^ f7) << 4);

    f32x4 acc[8][4] = {};
    half8 a0[4][2], a1[4][2], b0[2][2], b1[2][2];

    // prologue: tile 0 -> buf0, tile 1 -> buf1; wait tile 0; prime a0 of tile 0
    STAGE_A(0, 0); STAGE_B(0, 0);
    STAGE_A(64, 1); STAGE_B(64, 1);
    asm volatile("s_waitcnt vmcnt(8)" ::: "memory");
    __builtin_amdgcn_s_barrier();
    asm volatile("" ::: "memory");
    __builtin_amdgcn_sched_barrier(0);
    #pragma unroll
    for (int i = 0; i < 4; ++i) {
        a0[i][0] = *(const half8*)(pA0 + i * 2048);
        a0[i][1] = *(const half8*)(pA1 + i * 2048);
    }

    #define TILE(T_, CUR_, NXT_) do {                                             \
        const int _kt2 = ((T_) + 2) << 6;                                         \
        const bool _st = ((T_) < NT - 2);                                         \
        const bool _rd = ((T_) < NT - 1);                                         \
        /* ---- win1: read b0, a1; MFMA a0 x b0 ---- */                           \
        _Pragma("unroll")                                                         \
        for (int j = 0; j < 2; ++j) {                                             \
            b0[j][0] = *(const half8*)(pB0 + ((CUR_) * 32768 + j * 2048));        \
            b0[j][1] = *(const half8*)(pB1 + ((CUR_) * 32768 + j * 2048));        \
        }                                                                         \
        _Pragma("unroll")                                                         \
        for (int i = 0; i < 4; ++i) {                                             \
            a1[i][0] = *(const half8*)(pA0 + ((CUR_) * 32768 + (4 + i) * 2048));  \
            a1[i][1] = *(const half8*)(pA1 + ((CUR_) * 32768 + (4 + i) * 2048));  \
        }                                                                         \
        __builtin_amdgcn_s_setprio(1);                                            \
        _Pragma("unroll")                                                         \
        for (int i = 0; i < 4; ++i)                                               \
            _Pragma("unroll")                                                     \
            for (int j = 0; j < 2; ++j) {                                         \
                acc[i][j] = MFMA16(a0[i][0], b0[j][0], acc[i][j]);                \
                acc[i][j] = MFMA16(a0[i][1], b0[j][1], acc[i][j]);                \
            }                                                                     \
        __builtin_amdgcn_s_setprio(0);                                            \
        /* ---- read b1; MFMA a0 x b1 ---- */                                     \
        _Pragma("unroll")                                                         \
        for (int j = 0; j < 2; ++j) {                                             \
            b1[j][0] = *(const half8*)(pB0 + ((CUR_) * 32768 + (2 + j) * 2048));  \
            b1[j][1] = *(const half8*)(pB1 + ((CUR_) * 32768 + (2 + j) * 2048));  \
        }                                                                         \
        __builtin_amdgcn_s_setprio(1);                                            \
        _Pragma("unroll")                                                         \
        for (int i = 0; i < 4; ++i)                                               \
            _Pragma("unroll")                                                     \
            for (int j = 0; j < 2; ++j) {                                         \
                acc[i][2 + j] = MFMA16(a0[i][0], b1[j][0], acc[i][2 + j]);        \
                acc[i][2 + j] = MFMA16(a0[i][1], b1[j][1], acc[i][2 + j]);        \
            }                                                                     \
        __builtin_amdgcn_s_setprio(0);                                            \
        /* ---- B1: buf[cur] reads drained; A(t+1) resident everywhere ---- */    \
        asm volatile("s_waitcnt vmcnt(4) lgkmcnt(0)" ::: "memory");               \
        __builtin_amdgcn_sched_barrier(0);                                        \
        __builtin_amdgcn_s_barrier();                                             \
        asm volatile("" ::: "memory");                                            \
        __builtin_amdgcn_sched_barrier(0);                                        \
        /* ---- win2: stage A(t+2); prefetch a0 <- nxt; MFMA a1 x b0 ---- */      \
        if (_st) STAGE_A(_kt2, CUR_);                                             \
        if (_rd) {                                                                \
            _Pragma("unroll")                                                     \
            for (int i = 0; i < 4; ++i) {                                         \
                a0[i][0] = *(const half8*)(pA0 + ((NXT_) * 32768 + i * 2048));    \
                a0[i][1] = *(const half8*)(pA1 + ((NXT_) * 32768 + i * 2048));    \
            }                                                                     \
        }                                                                         \
        __builtin_amdgcn_s_setprio(1);                                            \
        _Pragma("unroll")                                                         \
        for (int i = 0; i < 4; ++i)                                               \
            _Pragma("unroll")                                                     \
            for (int j = 0; j < 2; ++j) {                                         \
                acc[4 + i][j] = MFMA16(a1[i][0], b0[j][0], acc[4 + i][j]);        \
                acc[4 + i][j] = MFMA16(a1[i][1], b0[j][1], acc[4 + i][j]);        \
            }                                                                     \
        __builtin_amdgcn_s_setprio(0);                                            \
        if (_st) STAGE_B(_kt2, CUR_);                                             \
        __builtin_amdgcn_s_setprio(1);                                            \
        _Pragma("unroll")                                                         \
        for (int i = 0; i < 4; ++i)                                               \
            _Pragma("unroll")                                                     \
            for (int j = 0; j < 2; ++j) {                                         \
                acc[4 + i][2 + j] = MFMA16(a1[i][0], b1[j][0], acc[4 + i][2 + j]);\
                acc[4 + i][2 + j] = MFMA16(a1[i][1], b1[j][1], acc[4 + i][2 + j]);\
            }                                                                     \
        __builtin_amdgcn_s_setprio(0);                                            \
        /* ---- B2: B(t+1) resident everywhere ---- */                            \
        if (_st) {                                                                \
            asm volatile("s_waitcnt vmcnt(8)" ::: "memory");                      \
        } else if ((T_) == NT - 2) {                                              \
            asm volatile("s_waitcnt vmcnt(0)" ::: "memory");                      \
        }                                                                         \
        __builtin_amdgcn_sched_barrier(0);                                        \
        __builtin_amdgcn_s_barrier();                                             \
        asm volatile("" ::: "memory");                                            \
        __builtin_amdgcn_sched_barrier(0);                                        \
    } while (0)

    for (int t = 0; t < NT; t += 2) {
        TILE(t, 0, 1);
        TILE(t + 1, 1, 0);
    }

    // ---- epilogue: out = acc*gamma + bias. C/D: col = fr, row = kg*4 + jj ----
    const float gamma = (float)fmax(*gsum * (1.0 / (double)NW_ELEMS), 1e-4);
    const int rbase = m0 + wm * 128 + (kg << 2);
    #pragma unroll
    for (int j = 0; j < 4; ++j) {
        const int gn = n0 + wn * 64 + j * 16 + fr;
        const float bv = bias[gn];
        #pragma unroll
        for (int i = 0; i < 8; ++i) {
            #pragma unroll
            for (int jj = 0; jj < 4; ++jj) {
                const int gm = rbase + i * 16 + jj;
                out[(size_t)gm * N_DIM + gn] = acc[i][j][jj] * gamma + bv;
            }
        }
    }
}

// ---------------- launch ----------------

extern "C" void kernel_launch(void* const* d_in, const int* in_sizes, int n_in,
                              void* d_out, int out_size, void* d_ws, size_t ws_size,
                              hipStream_t stream) {
    const float* x = (const float*)d_in[0];
    const float* w = (const float*)d_in[1];
    const float* bias = (const float*)d_in[2];
    float* out = (float*)d_out;

    char* ws = (char*)d_ws;
    double* gsum = (double*)ws;
    _Float16* x16 = (_Float16*)(ws + 256);
    _Float16* w16 = (_Float16*)(ws + 256 + (size_t)NX_ELEMS * 2);

    zero_gsum<<<1, 1, 0, stream>>>(gsum);
    gamma_reduce<<<2048, 256, 0, stream>>>((const float4*)w, gsum, NW_ELEMS / 4);
    quant_w<<<NW_ELEMS / 8 / 256, 256, 0, stream>>>((const float4*)w, (half8*)w16, gsum);
    cvt_x<<<NX_ELEMS / 8 / 256, 256, 0, stream>>>((const float4*)x, (half8*)x16);

    const int nblk = (M_DIM / 256) * (N_DIM / 256);   // 2048
    gemm_kernel<<<nblk, 512, 0, stream>>>(x16, w16, bias, gsum, out);
}